// Round 12
// baseline (211.330 us; speedup 1.0000x reference)
//
#include <hip/hip_runtime.h>
#include <cmath>

#define B 64
#define S 400
#define H 512
#define E 256
#define V 50000
#define OOV 100
#define H2 1024
#define VDN (V + OOV)   // 50100
#define NBLK_V 782      // ceil(V/64)
#define SC 8            // ctx s-chunks (50 s each)

typedef __attribute__((ext_vector_type(8))) short short8;
typedef __attribute__((ext_vector_type(4))) float f32x4;

__device__ __forceinline__ float wred_sum(float v) {
#pragma unroll
  for (int o = 32; o > 0; o >>= 1) v += __shfl_down(v, o, 64);
  return v;
}
__device__ __forceinline__ float wred_max(float v) {
#pragma unroll
  for (int o = 32; o > 0; o >>= 1) v = fmaxf(v, __shfl_down(v, o, 64));
  return v;
}
__device__ __forceinline__ short f2bf(float f) {
  return __builtin_bit_cast(short, (__bf16)f);
}
__device__ __forceinline__ float bf2f(unsigned short u) {
  unsigned x = (unsigned)u << 16;
  return __builtin_bit_cast(float, x);
}
__device__ __forceinline__ float ftanh(float x) {
  float e = __expf(2.f * x);
  return 1.f - 2.f * __builtin_amdgcn_rcpf(e + 1.f);
}
__device__ __forceinline__ float fsig(float x) {
  return __builtin_amdgcn_rcpf(1.f + __expf(-x));
}

// ---- fused: bias-init GEMM outputs + pack catT4/h0T4 + zero Zb ----
__global__ __launch_bounds__(256) void k_pre(
    const float* __restrict__ b_ctx, const float* __restrict__ b_ih,
    const float* __restrict__ b_hh, const float* __restrict__ b_feat,
    const float* __restrict__ b_o1, const float* __restrict__ context,
    const float* __restrict__ emb, const int* __restrict__ sumin,
    const float* __restrict__ h0, float* __restrict__ ctxoutT4,
    float* __restrict__ gates, float* __restrict__ dfeat,
    float* __restrict__ innerT4, float* __restrict__ catT4,
    float* __restrict__ h0T4, float* __restrict__ Zb) {
  int idx = blockIdx.x * 256 + threadIdx.x;  // < 360448
  if (idx < 64) Zb[idx] = 0.f;
  if (idx < 16384) {
    int j = ((idx >> 8) << 2) + (idx & 3);
    ctxoutT4[idx] = b_ctx[j];
  } else if (idx < 16384 + 131072) {
    int i = idx - 16384;
    int j = i & 2047;
    gates[i] = b_ih[j] + b_hh[j];
  } else if (idx < 16384 + 131072 + 65536) {
    int i = idx - 16384 - 131072;
    dfeat[i] = b_feat[i & 1023];
  } else if (idx < 245760) {
    int i = idx - 16384 - 131072 - 65536;
    int j = ((i >> 8) << 2) + (i & 3);
    innerT4[i] = b_o1[j];
  } else if (idx < 245760 + 81920) {
    int i = idx - 245760;
    int e = i & 3, b = (i >> 2) & 63, q = i >> 8;
    int k = q * 4 + e;
    catT4[i] = (k < 1024) ? context[b * 1024 + k]
                          : emb[(size_t)sumin[b] * 256 + (k - 1024)];
  } else {
    int i = idx - 245760 - 81920;  // < 32768
    int e = i & 3, b = (i >> 2) & 63, q = i >> 8;
    h0T4[i] = h0[b * 512 + q * 4 + e];
  }
}

// ---- split-K skinny GEMM, atomic accumulate into bias-initialized out ----
template <int R, int KC, int OUTMODE>
__global__ __launch_bounds__(256) void k_gemmsk(
    const float* __restrict__ A1, const float* __restrict__ W1, int ldw1, int s1,
    const float* __restrict__ A2, const float* __restrict__ W2, int ldw2,
    float* __restrict__ out, int ldout) {
  const int lane = threadIdx.x;
  const int w = threadIdx.y;
  const int j0 = blockIdx.x * (4 * R) + w * R;
  const float* A;
  const float* W;
  int ldw, kc0;
  if ((int)blockIdx.y < s1) {
    A = A1; W = W1; ldw = ldw1; kc0 = blockIdx.y * KC;
  } else {
    A = A2; W = W2; ldw = ldw2; kc0 = (blockIdx.y - s1) * KC;
  }
  float acc[R];
#pragma unroll
  for (int r = 0; r < R; ++r) acc[r] = 0.f;
  const float* ap = A + (size_t)kc0 * 256 + lane * 4;
  const float* wr[R];
#pragma unroll
  for (int r = 0; r < R; ++r) wr[r] = W + (size_t)(j0 + r) * ldw + kc0 * 4;
#pragma unroll 8
  for (int k4 = 0; k4 < KC; ++k4) {
    float4 av = *(const float4*)(ap + (size_t)k4 * 256);
#pragma unroll
    for (int r = 0; r < R; ++r) {
      float4 wv = *(const float4*)(wr[r] + k4 * 4);
      acc[r] += av.x * wv.x + av.y * wv.y + av.z * wv.z + av.w * wv.w;
    }
  }
#pragma unroll
  for (int r = 0; r < R; ++r) {
    int j = j0 + r;
    if constexpr (OUTMODE == 0)
      atomicAdd(&out[((size_t)(j >> 2) * 64 + lane) * 4 + (j & 3)], acc[r]);
    else
      atomicAdd(&out[(size_t)lane * ldout + j], acc[r]);
  }
}

// ---- LSTM pointwise: hidden=[h|c] row-major (d_out) + hidcat T4 ----
__global__ __launch_bounds__(256) void k_lstm(const float* __restrict__ gates,
                                              const float* __restrict__ c0,
                                              float* __restrict__ hidden,
                                              float* __restrict__ hcT4) {
  int idx = blockIdx.x * 256 + threadIdx.x;  // 32768
  int b = idx >> 9, u = idx & 511;
  float gi = gates[(size_t)b * 2048 + u];
  float gf = gates[(size_t)b * 2048 + 512 + u];
  float gg = gates[(size_t)b * 2048 + 1024 + u];
  float go = gates[(size_t)b * 2048 + 1536 + u];
  float c = fsig(gf) * c0[(size_t)b * 512 + u] + fsig(gi) * ftanh(gg);
  float h = fsig(go) * ftanh(c);
  hidden[(size_t)b * H2 + u] = h;
  hidden[(size_t)b * H2 + 512 + u] = c;
  hcT4[((u >> 2) * 64 + b) * 4 + (u & 3)] = h;
  int k = 512 + u;
  hcT4[((k >> 2) * 64 + b) * 4 + (k & 3)] = c;
}

// ---- attention scores: two-phase (8 hoisted loads), fused mask*exp, Z atomic --
__global__ __launch_bounds__(256) void k_e(
    const float* __restrict__ ef, const float* __restrict__ dfeat,
    const float* __restrict__ cov, const float* __restrict__ Wcov,
    const float* __restrict__ bcov, const float* __restrict__ watt,
    const float* __restrict__ batt, const float* __restrict__ mask,
    float* __restrict__ e_x, float* __restrict__ Zb) {
  const int t = threadIdx.x;
  const int b = blockIdx.x & 63;
  const int q = blockIdx.x >> 6;  // 0..49
  float4 dv = ((const float4*)(dfeat + (size_t)b * H2))[t];
  float4 bc = ((const float4*)bcov)[t];
  float4 wc = ((const float4*)Wcov)[t];
  float4 wa = ((const float4*)watt)[t];
  const float bx = dv.x + bc.x, by = dv.y + bc.y;
  const float bz = dv.z + bc.z, bw = dv.w + bc.w;
  // phase A: all 8 row loads issued back-to-back (8 in flight)
  float4 evs[8];
  float cvals[8];
#pragma unroll
  for (int i = 0; i < 8; ++i) {
    const int sb = (q * 8 + i) * B + b;
    evs[i] = ((const float4*)(ef + (size_t)sb * H2))[t];
    cvals[i] = cov[sb];
  }
  // phase B+C: compute + reduce
  __shared__ float part[8][4];
#pragma unroll
  for (int i = 0; i < 8; ++i) {
    float sum = ftanh(evs[i].x + bx + cvals[i] * wc.x) * wa.x +
                ftanh(evs[i].y + by + cvals[i] * wc.y) * wa.y +
                ftanh(evs[i].z + bz + cvals[i] * wc.z) * wa.z +
                ftanh(evs[i].w + bw + cvals[i] * wc.w) * wa.w;
    sum = wred_sum(sum);
    if ((t & 63) == 0) part[i][t >> 6] = sum;
  }
  __syncthreads();
  // x = mask * exp(e) (no max subtraction; |e| small), block-partial Z
  if (t < 64) {
    float x = 0.f;
    if (t < 8) {
      int sb = (q * 8 + t) * B + b;
      float e = part[t][0] + part[t][1] + part[t][2] + part[t][3] + batt[0];
      x = mask[sb] * __expf(e);
      e_x[sb] = x;
    }
#pragma unroll
    for (int o = 4; o > 0; o >>= 1) x += __shfl_down(x, o, 64);
    if (t == 0) atomicAdd(&Zb[b], x);
  }
}

// ---- fused a = x/Z + ctx einsum chunk (no softmax recompute) ----
__global__ __launch_bounds__(256) void k_softctx(
    const float* __restrict__ e_x, const float* __restrict__ Zb,
    const float* __restrict__ coverage, const float* __restrict__ enc,
    float* __restrict__ a_out, float* __restrict__ cov_out,
    float* __restrict__ part) {
  const int b = blockIdx.x & 63;
  const int sc = blockIdx.x >> 6;
  const int t = threadIdx.x;
  __shared__ float aS[50];
  const float rZ = 1.f / Zb[b];
  if (t < 50) {
    int s = sc * 50 + t;
    int sb = s * B + b;
    float av = e_x[sb] * rZ;
    aS[t] = av;
    a_out[sb] = av;
    cov_out[sb] = coverage[sb] + av;
  }
  __syncthreads();
  const int d = t * 4;
  float4 acc = make_float4(0.f, 0.f, 0.f, 0.f);
#pragma unroll 10
  for (int i = 0; i < 50; ++i) {
    int s = sc * 50 + i;
    float av = aS[i];
    float4 ev = *(const float4*)(enc + ((size_t)b * S + s) * H2 + d);
    acc.x += av * ev.x;
    acc.y += av * ev.y;
    acc.z += av * ev.z;
    acc.w += av * ev.w;
  }
  *(float4*)(part + (size_t)blockIdx.x * H2 + d) = acc;
}

// ---- fused: reduce 8 ctx partials -> ctx_new/T4 + p_gen (block = b) ----
__global__ __launch_bounds__(256) void k_ctxpg(
    const float* __restrict__ part, const float* __restrict__ hidden,
    const float* __restrict__ ctxoutT4, const float* __restrict__ Wpg,
    const float* __restrict__ bpg, float* __restrict__ ctx_new,
    float* __restrict__ ctxT4, float* __restrict__ pgen) {
  const int b = blockIdx.x;
  const int t = threadIdx.x;
  const int lane = t & 63, w = t >> 6;
  const int d = t * 4;
  float4 s = make_float4(0.f, 0.f, 0.f, 0.f);
#pragma unroll
  for (int sc = 0; sc < SC; ++sc) {
    float4 v = *(const float4*)(part + (size_t)(sc * 64 + b) * H2 + d);
    s.x += v.x; s.y += v.y; s.z += v.z; s.w += v.w;
  }
  *(float4*)(ctx_new + (size_t)b * H2 + d) = s;
  *(float4*)(ctxT4 + (size_t)t * 256 + b * 4) = s;
  float p = s.x * Wpg[d] + s.y * Wpg[d + 1] + s.z * Wpg[d + 2] + s.w * Wpg[d + 3];
#pragma unroll
  for (int j = 0; j < 4; ++j) {
    int k = t + j * 256;
    p += hidden[(size_t)b * H2 + k] * Wpg[1024 + k];
  }
  p += ctxoutT4[(size_t)(t >> 2) * 256 + b * 4 + (t & 3)] * Wpg[2048 + t];
  p = wred_sum(p);
  __shared__ float red[4];
  if (lane == 0) red[w] = p;
  __syncthreads();
  if (t == 0) {
    float dd = red[0] + red[1] + red[2] + red[3] + bpg[0];
    pgen[b] = fsig(dd);
  }
}

// ---- pack inner into MFMA B-fragments ----
__global__ __launch_bounds__(256) void k_packinner(const float* __restrict__ innerT4,
                                                   short8* __restrict__ packB) {
  int f = blockIdx.x * 256 + threadIdx.x;  // < 4096
  int l = f & 63, bt = (f >> 6) & 3, ks = f >> 8;
  int b = bt * 16 + (l & 15);
  int kbase = ks * 32 + (l >> 4) * 8;
  float4 q0 = *(const float4*)&innerT4[(size_t)(kbase / 4) * 256 + b * 4];
  float4 q1 = *(const float4*)&innerT4[(size_t)(kbase / 4 + 1) * 256 + b * 4];
  short8 frag;
  frag[0] = f2bf(q0.x); frag[1] = f2bf(q0.y);
  frag[2] = f2bf(q0.z); frag[3] = f2bf(q0.w);
  frag[4] = f2bf(q1.x); frag[5] = f2bf(q1.y);
  frag[6] = f2bf(q1.z); frag[7] = f2bf(q1.w);
  packB[f] = frag;
}

// ---- logits via bf16 MFMA, bf16 logits store, fused softmax partials ----
__global__ __launch_bounds__(256) void k_mfma_logits(
    const float* __restrict__ W2, const short8* __restrict__ packB,
    const float* __restrict__ bias, unsigned short* __restrict__ logits_bf,
    float* __restrict__ mp, float* __restrict__ zp) {
  const int l = threadIdx.x;
  const int w = threadIdx.y;
  const int jblk = blockIdx.x * 64;
  const int jv = min(jblk + w * 16 + (l & 15), V - 1);
  const float4* wp4 = (const float4*)(W2 + (size_t)jv * 512 + (l >> 4) * 8);

  f32x4 acc0 = {0.f, 0.f, 0.f, 0.f}, acc1 = acc0, acc2 = acc0, acc3 = acc0;
  float4 cw0 = wp4[0], cw1 = wp4[1];
#pragma unroll
  for (int ks = 0; ks < 16; ++ks) {
    float4 nw0, nw1;
    if (ks < 15) { nw0 = wp4[(ks + 1) * 8]; nw1 = wp4[(ks + 1) * 8 + 1]; }
    short8 af;
    af[0] = f2bf(cw0.x); af[1] = f2bf(cw0.y); af[2] = f2bf(cw0.z); af[3] = f2bf(cw0.w);
    af[4] = f2bf(cw1.x); af[5] = f2bf(cw1.y); af[6] = f2bf(cw1.z); af[7] = f2bf(cw1.w);
    short8 b0 = packB[(ks * 4 + 0) * 64 + l];
    short8 b1 = packB[(ks * 4 + 1) * 64 + l];
    short8 b2 = packB[(ks * 4 + 2) * 64 + l];
    short8 b3 = packB[(ks * 4 + 3) * 64 + l];
    acc0 = __builtin_amdgcn_mfma_f32_16x16x32_bf16(af, b0, acc0, 0, 0, 0);
    acc1 = __builtin_amdgcn_mfma_f32_16x16x32_bf16(af, b1, acc1, 0, 0, 0);
    acc2 = __builtin_amdgcn_mfma_f32_16x16x32_bf16(af, b2, acc2, 0, 0, 0);
    acc3 = __builtin_amdgcn_mfma_f32_16x16x32_bf16(af, b3, acc3, 0, 0, 0);
    if (ks < 15) { cw0 = nw0; cw1 = nw1; }
  }

  __shared__ float tile[64][65];
  const int rbase = w * 16 + (l >> 4) * 4;
#pragma unroll
  for (int v = 0; v < 4; ++v) {
    int jl = rbase + v;
    int j = jblk + jl;
    float bv = bias[min(j, V - 1)];
    bool valid = (j < V);
    tile[jl][0 * 16 + (l & 15)] = valid ? acc0[v] + bv : -INFINITY;
    tile[jl][1 * 16 + (l & 15)] = valid ? acc1[v] + bv : -INFINITY;
    tile[jl][2 * 16 + (l & 15)] = valid ? acc2[v] + bv : -INFINITY;
    tile[jl][3 * 16 + (l & 15)] = valid ? acc3[v] + bv : -INFINITY;
  }
  __syncthreads();
  const int t = w * 64 + l;
#pragma unroll
  for (int i = 0; i < 16; ++i) {
    int idx = i * 256 + t;
    int jl = idx & 63;
    int b = idx >> 6;
    int j = jblk + jl;
    if (j < V)
      logits_bf[(size_t)b * V + j] = (unsigned short)f2bf(tile[jl][b]);
  }
  if (t < 64) {
    float m = -INFINITY;
#pragma unroll
    for (int jl = 0; jl < 64; ++jl) m = fmaxf(m, tile[jl][t]);
    float z = 0.f;
#pragma unroll
    for (int jl = 0; jl < 64; ++jl) z += __expf(tile[jl][t] - m);
    mp[(size_t)blockIdx.x * 64 + t] = m;
    zp[(size_t)blockIdx.x * 64 + t] = z;
  }
}

// ---- fused: (M,Z) reduce + vd = p_gen*softmax + LDS-hist scatter ----
__global__ __launch_bounds__(256) void k_vdms(
    const unsigned short* __restrict__ logits_bf, const float* __restrict__ mp,
    const float* __restrict__ zp, const float* __restrict__ pgen,
    const float* __restrict__ a_out, const int* __restrict__ tex,
    float* __restrict__ out) {
  const int b = blockIdx.x >> 3;
  const int c = blockIdx.x & 7;
  const int t = threadIdx.x;
  const int lane = t & 63, w = t >> 6;
  __shared__ float red[4];
  __shared__ float hist[6272];
  float m = -INFINITY;
  for (int i = t; i < NBLK_V; i += 256) m = fmaxf(m, mp[i * 64 + b]);
  m = wred_max(m);
  if (lane == 0) red[w] = m;
  __syncthreads();
  const float M = fmaxf(fmaxf(red[0], red[1]), fmaxf(red[2], red[3]));
  __syncthreads();
  float z = 0.f;
  for (int i = t; i < NBLK_V; i += 256) z += zp[i * 64 + b] * __expf(mp[i * 64 + b] - M);
  z = wred_sum(z);
  if (lane == 0) red[w] = z;
  __syncthreads();
  const float Z = red[0] + red[1] + red[2] + red[3];
  const float pg = pgen[b];
  const float scale = pg / Z;
  const float wq = 1.f - pg;
  const int v0 = c * 6272;
  const int v1 = min(v0 + 6272, VDN);
  for (int i = t; i < 6272; i += 256) hist[i] = 0.f;
  __syncthreads();
  for (int s = t; s < S; s += 256) {
    int v = tex[s * B + b];
    if (v >= v0 && v < v1) atomicAdd(&hist[v - v0], wq * a_out[s * B + b]);
  }
  __syncthreads();
  for (int v = v0 + t; v < v1; v += 256) {
    float val =
        (v < V) ? scale * __expf(bf2f(logits_bf[(size_t)b * V + v]) - M) : 0.f;
    out[(size_t)b * VDN + v] = val + hist[v - v0];
  }
}

extern "C" void kernel_launch(void* const* d_in, const int* in_sizes, int n_in,
                              void* d_out, int out_size, void* d_ws, size_t ws_size,
                              hipStream_t stream) {
  const int* sumin = (const int*)d_in[0];
  const float* h0 = (const float*)d_in[1];
  const float* c0 = (const float*)d_in[2];
  const float* enc_out = (const float*)d_in[3];
  const float* ef = (const float*)d_in[4];
  const float* mask = (const float*)d_in[5];
  const float* context = (const float*)d_in[6];
  const float* coverage = (const float*)d_in[7];
  const int* tex = (const int*)d_in[8];
  const float* emb = (const float*)d_in[10];
  const float* W_feat = (const float*)d_in[11];
  const float* b_feat = (const float*)d_in[12];
  const float* W_cov = (const float*)d_in[13];
  const float* b_cov = (const float*)d_in[14];
  const float* w_att = (const float*)d_in[15];
  const float* b_att = (const float*)d_in[16];
  const float* W_ih = (const float*)d_in[17];
  const float* W_hh = (const float*)d_in[18];
  const float* b_ih = (const float*)d_in[19];
  const float* b_hh = (const float*)d_in[20];
  const float* W_ctx = (const float*)d_in[21];
  const float* b_ctx = (const float*)d_in[22];
  const float* W_pg = (const float*)d_in[23];
  const float* b_pg = (const float*)d_in[24];
  const float* W_o1 = (const float*)d_in[25];
  const float* b_o1 = (const float*)d_in[26];
  const float* W_o2 = (const float*)d_in[27];
  const float* b_o2 = (const float*)d_in[28];

  float* out = (float*)d_out;
  float* vd = out;                           // [64][50100]
  float* hidden = vd + (size_t)B * VDN;      // [64][1024] = [h|c]
  float* ctx_new = hidden + (size_t)B * H2;  // [64][1024]
  float* a_out = ctx_new + (size_t)B * H2;   // [400][64]
  float* cov_out = a_out + (size_t)S * B;    // [400][64]

  float* ws = (float*)d_ws;
  float* catT4 = ws;                   // 81920
  float* h0T4 = catT4 + 81920;         // 32768
  float* ctxoutT4 = h0T4 + 32768;      // 16384
  float* gates = ctxoutT4 + 16384;     // 131072
  float* hidcatT4 = gates + 131072;    // 65536
  float* dfeat = hidcatT4 + 65536;     // 65536
  float* e_x = dfeat + 65536;          // 25600
  float* ctxnewT4 = e_x + 25600;       // 65536
  float* innerT4 = ctxnewT4 + 65536;   // 32768
  float* pgen = innerT4 + 32768;       // 64
  float* Zb = pgen + 64;               // 64
  float* mp = Zb + 64;                 // 50048
  float* zp = mp + 50048;              // 50048
  float* packBf = zp + 50048;          // 16384 floats = 4096 short8
  float* logits = packBf + 16384;      // 1600000 floats as ushort area
  float* part = logits + 1600064;      // 8*65536 = 524288
  short8* packB = (short8*)packBf;
  unsigned short* logits_bf = (unsigned short*)logits;

  dim3 gblk(64, 4);

  k_pre<<<1408, 256, 0, stream>>>(b_ctx, b_ih, b_hh, b_feat, b_o1, context, emb,
                                  sumin, h0, ctxoutT4, gates, dfeat, innerT4,
                                  catT4, h0T4, Zb);
  // ctx_out += [context|x] @ W_ctx.T   (T4 out)
  k_gemmsk<2, 64, 0><<<dim3(32, 5), gblk, 0, stream>>>(
      catT4, W_ctx, 1280, 5, nullptr, nullptr, 0, ctxoutT4, 0);
  // gates += ctx_out@W_ih.T  and  h0@W_hh.T   (row-major out)
  k_gemmsk<2, 64, 1><<<dim3(256, 3), gblk, 0, stream>>>(
      ctxoutT4, W_ih, 256, 1, h0T4, W_hh, 512, gates, 2048);
  k_lstm<<<128, 256, 0, stream>>>(gates, c0, hidden, hidcatT4);
  // dec_feat += hidden @ W_feat.T   (row-major out)
  k_gemmsk<2, 64, 1><<<dim3(128, 4), gblk, 0, stream>>>(
      hidcatT4, W_feat, 1024, 4, nullptr, nullptr, 0, dfeat, 1024);
  // e -> x = mask*exp(e), Z[b] accumulated
  k_e<<<50 * 64, 256, 0, stream>>>(ef, dfeat, coverage, W_cov, b_cov, w_att,
                                   b_att, mask, e_x, Zb);
  // a = x/Z + ctx einsum chunks (writes a_out/cov_out outputs too)
  k_softctx<<<SC * B, 256, 0, stream>>>(e_x, Zb, coverage, enc_out, a_out,
                                        cov_out, part);
  // fused ctx reduce + p_gen
  k_ctxpg<<<B, 256, 0, stream>>>(part, hidden, ctxoutT4, W_pg, b_pg, ctx_new,
                                 ctxnewT4, pgen);
  // inner += h@W_o1[:, :512].T  and  ctx_new@W_o1[:, 512:].T   (T4 out)
  k_gemmsk<2, 64, 0><<<dim3(64, 6), gblk, 0, stream>>>(
      hidcatT4, W_o1, 1536, 2, ctxnewT4, W_o1 + 512, 1536, innerT4, 0);
  k_packinner<<<16, 256, 0, stream>>>(innerT4, packB);
  k_mfma_logits<<<NBLK_V, gblk, 0, stream>>>(W_o2, packB, b_o2, logits_bf, mp, zp);
  // fused (M,Z) + vd write + LDS-hist scatter
  k_vdms<<<B * 8, 256, 0, stream>>>(logits_bf, mp, zp, pgen, a_out, tex, vd);
}

// Round 13
// 207.065 us; speedup vs baseline: 1.0206x; 1.0206x over previous
//
#include <hip/hip_runtime.h>
#include <cmath>

#define B 64
#define S 400
#define H 512
#define E 256
#define V 50000
#define OOV 100
#define H2 1024
#define VDN (V + OOV)   // 50100
#define NBLK_V 782      // ceil(V/64)
#define SC 50           // ctx partial chunks (8 s each)

typedef __attribute__((ext_vector_type(8))) short short8;
typedef __attribute__((ext_vector_type(4))) float f32x4;

__device__ __forceinline__ float wred_sum(float v) {
#pragma unroll
  for (int o = 32; o > 0; o >>= 1) v += __shfl_down(v, o, 64);
  return v;
}
__device__ __forceinline__ float wred_max(float v) {
#pragma unroll
  for (int o = 32; o > 0; o >>= 1) v = fmaxf(v, __shfl_down(v, o, 64));
  return v;
}
__device__ __forceinline__ short f2bf(float f) {
  return __builtin_bit_cast(short, (__bf16)f);
}
__device__ __forceinline__ float bf2f(unsigned short u) {
  unsigned x = (unsigned)u << 16;
  return __builtin_bit_cast(float, x);
}
__device__ __forceinline__ float ftanh(float x) {
  float e = __expf(2.f * x);
  return 1.f - 2.f * __builtin_amdgcn_rcpf(e + 1.f);
}
__device__ __forceinline__ float fsig(float x) {
  return __builtin_amdgcn_rcpf(1.f + __expf(-x));
}

// ---- fused: bias-init GEMM outputs + pack catT4/h0T4 + zero Zb ----
__global__ __launch_bounds__(256) void k_pre(
    const float* __restrict__ b_ctx, const float* __restrict__ b_ih,
    const float* __restrict__ b_hh, const float* __restrict__ b_feat,
    const float* __restrict__ b_o1, const float* __restrict__ context,
    const float* __restrict__ emb, const int* __restrict__ sumin,
    const float* __restrict__ h0, float* __restrict__ ctxoutT4,
    float* __restrict__ gates, float* __restrict__ dfeat,
    float* __restrict__ innerT4, float* __restrict__ catT4,
    float* __restrict__ h0T4, float* __restrict__ Zb) {
  int idx = blockIdx.x * 256 + threadIdx.x;  // < 360448
  if (idx < 64) Zb[idx] = 0.f;
  if (idx < 16384) {
    int j = ((idx >> 8) << 2) + (idx & 3);
    ctxoutT4[idx] = b_ctx[j];
  } else if (idx < 16384 + 131072) {
    int i = idx - 16384;
    int j = i & 2047;
    gates[i] = b_ih[j] + b_hh[j];
  } else if (idx < 16384 + 131072 + 65536) {
    int i = idx - 16384 - 131072;
    dfeat[i] = b_feat[i & 1023];
  } else if (idx < 245760) {
    int i = idx - 16384 - 131072 - 65536;
    int j = ((i >> 8) << 2) + (i & 3);
    innerT4[i] = b_o1[j];
  } else if (idx < 245760 + 81920) {
    int i = idx - 245760;
    int e = i & 3, b = (i >> 2) & 63, q = i >> 8;
    int k = q * 4 + e;
    catT4[i] = (k < 1024) ? context[b * 1024 + k]
                          : emb[(size_t)sumin[b] * 256 + (k - 1024)];
  } else {
    int i = idx - 245760 - 81920;  // < 32768
    int e = i & 3, b = (i >> 2) & 63, q = i >> 8;
    h0T4[i] = h0[b * 512 + q * 4 + e];
  }
}

// ---- split-K skinny GEMM, atomic accumulate into bias-initialized out ----
template <int R, int KC, int OUTMODE>
__global__ __launch_bounds__(256) void k_gemmsk(
    const float* __restrict__ A1, const float* __restrict__ W1, int ldw1, int s1,
    const float* __restrict__ A2, const float* __restrict__ W2, int ldw2,
    float* __restrict__ out, int ldout) {
  const int lane = threadIdx.x;
  const int w = threadIdx.y;
  const int j0 = blockIdx.x * (4 * R) + w * R;
  const float* A;
  const float* W;
  int ldw, kc0;
  if ((int)blockIdx.y < s1) {
    A = A1; W = W1; ldw = ldw1; kc0 = blockIdx.y * KC;
  } else {
    A = A2; W = W2; ldw = ldw2; kc0 = (blockIdx.y - s1) * KC;
  }
  float acc[R];
#pragma unroll
  for (int r = 0; r < R; ++r) acc[r] = 0.f;
  const float* ap = A + (size_t)kc0 * 256 + lane * 4;
  const float* wr[R];
#pragma unroll
  for (int r = 0; r < R; ++r) wr[r] = W + (size_t)(j0 + r) * ldw + kc0 * 4;
#pragma unroll 8
  for (int k4 = 0; k4 < KC; ++k4) {
    float4 av = *(const float4*)(ap + (size_t)k4 * 256);
#pragma unroll
    for (int r = 0; r < R; ++r) {
      float4 wv = *(const float4*)(wr[r] + k4 * 4);
      acc[r] += av.x * wv.x + av.y * wv.y + av.z * wv.z + av.w * wv.w;
    }
  }
#pragma unroll
  for (int r = 0; r < R; ++r) {
    int j = j0 + r;
    if constexpr (OUTMODE == 0)
      atomicAdd(&out[((size_t)(j >> 2) * 64 + lane) * 4 + (j & 3)], acc[r]);
    else
      atomicAdd(&out[(size_t)lane * ldout + j], acc[r]);
  }
}

// ---- LSTM pointwise: hidden=[h|c] row-major (d_out) + hidcat T4 ----
__global__ __launch_bounds__(256) void k_lstm(const float* __restrict__ gates,
                                              const float* __restrict__ c0,
                                              float* __restrict__ hidden,
                                              float* __restrict__ hcT4) {
  int idx = blockIdx.x * 256 + threadIdx.x;  // 32768
  int b = idx >> 9, u = idx & 511;
  float gi = gates[(size_t)b * 2048 + u];
  float gf = gates[(size_t)b * 2048 + 512 + u];
  float gg = gates[(size_t)b * 2048 + 1024 + u];
  float go = gates[(size_t)b * 2048 + 1536 + u];
  float c = fsig(gf) * c0[(size_t)b * 512 + u] + fsig(gi) * ftanh(gg);
  float h = fsig(go) * ftanh(c);
  hidden[(size_t)b * H2 + u] = h;
  hidden[(size_t)b * H2 + 512 + u] = c;
  hcT4[((u >> 2) * 64 + b) * 4 + (u & 3)] = h;
  int k = 512 + u;
  hcT4[((k >> 2) * 64 + b) * 4 + (k & 3)] = c;
}

// ---- fused attention: e -> x = mask*exp(e), Z atomic, AND x·enc partials ----
// grid: q*64+b (q<50). Both 105MB streams (ef, enc) issued concurrently.
__global__ __launch_bounds__(256) void k_ectx(
    const float* __restrict__ ef, const float* __restrict__ dfeat,
    const float* __restrict__ cov, const float* __restrict__ Wcov,
    const float* __restrict__ bcov, const float* __restrict__ watt,
    const float* __restrict__ batt, const float* __restrict__ mask,
    const float* __restrict__ enc, float* __restrict__ e_x,
    float* __restrict__ Zb, float* __restrict__ partc) {
  const int t = threadIdx.x;
  const int b = blockIdx.x & 63;
  const int q = blockIdx.x >> 6;  // 0..49
  float4 dv = ((const float4*)(dfeat + (size_t)b * H2))[t];
  float4 bc = ((const float4*)bcov)[t];
  float4 wc = ((const float4*)Wcov)[t];
  float4 wa = ((const float4*)watt)[t];
  const float bx = dv.x + bc.x, by = dv.y + bc.y;
  const float bz = dv.z + bc.z, bw = dv.w + bc.w;
  // both streams hoisted: 8 ef rows + 8 enc rows in flight together
  float4 evs[8], encs[8];
  float cvals[8];
#pragma unroll
  for (int i = 0; i < 8; ++i) {
    const int s = q * 8 + i;
    evs[i] = ((const float4*)(ef + (size_t)(s * B + b) * H2))[t];
    encs[i] = ((const float4*)(enc + ((size_t)b * S + s) * H2))[t];
    cvals[i] = cov[s * B + b];
  }
  __shared__ float ered[8][4];
  __shared__ float xS[8];
#pragma unroll
  for (int i = 0; i < 8; ++i) {
    float sum = ftanh(evs[i].x + bx + cvals[i] * wc.x) * wa.x +
                ftanh(evs[i].y + by + cvals[i] * wc.y) * wa.y +
                ftanh(evs[i].z + bz + cvals[i] * wc.z) * wa.z +
                ftanh(evs[i].w + bw + cvals[i] * wc.w) * wa.w;
    sum = wred_sum(sum);
    if ((t & 63) == 0) ered[i][t >> 6] = sum;
  }
  __syncthreads();
  if (t < 64) {
    float x = 0.f;
    if (t < 8) {
      int sb = (q * 8 + t) * B + b;
      float e = ered[t][0] + ered[t][1] + ered[t][2] + ered[t][3] + batt[0];
      x = mask[sb] * __expf(e);
      e_x[sb] = x;
      xS[t] = x;
    }
#pragma unroll
    for (int o = 4; o > 0; o >>= 1) x += __shfl_down(x, o, 64);
    if (t == 0) atomicAdd(&Zb[b], x);
  }
  __syncthreads();
  // unnormalized ctx partial from registers (enc already loaded)
  float4 acc = make_float4(0.f, 0.f, 0.f, 0.f);
#pragma unroll
  for (int i = 0; i < 8; ++i) {
    float x = xS[i];
    acc.x += x * encs[i].x;
    acc.y += x * encs[i].y;
    acc.z += x * encs[i].z;
    acc.w += x * encs[i].w;
  }
  ((float4*)(partc + (size_t)blockIdx.x * H2))[t] = acc;
}

// ---- fused: reduce 50 partials, scale 1/Z -> ctx outputs + p_gen + a/cov ----
__global__ __launch_bounds__(256) void k_ctxpg(
    const float* __restrict__ partc, const float* __restrict__ e_x,
    const float* __restrict__ Zb, const float* __restrict__ coverage,
    const float* __restrict__ hidden, const float* __restrict__ ctxoutT4,
    const float* __restrict__ Wpg, const float* __restrict__ bpg,
    float* __restrict__ ctx_new, float* __restrict__ ctxT4,
    float* __restrict__ pgen, float* __restrict__ a_out,
    float* __restrict__ cov_out) {
  const int b = blockIdx.x;
  const int t = threadIdx.x;
  const int lane = t & 63, w = t >> 6;
  const float rZ = 1.f / Zb[b];
  const int d = t * 4;
  float4 s = make_float4(0.f, 0.f, 0.f, 0.f);
#pragma unroll 10
  for (int sc = 0; sc < SC; ++sc) {
    float4 v = *(const float4*)(partc + (size_t)(sc * 64 + b) * H2 + d);
    s.x += v.x; s.y += v.y; s.z += v.z; s.w += v.w;
  }
  s.x *= rZ; s.y *= rZ; s.z *= rZ; s.w *= rZ;
  *(float4*)(ctx_new + (size_t)b * H2 + d) = s;
  *(float4*)(ctxT4 + (size_t)t * 256 + b * 4) = s;
  // a_out / cov_out (normalized attention weights)
#pragma unroll
  for (int i = 0; i < 2; ++i) {
    int sidx = t + i * 256;
    if (sidx < S) {
      int sb = sidx * B + b;
      float av = e_x[sb] * rZ;
      a_out[sb] = av;
      cov_out[sb] = coverage[sb] + av;
    }
  }
  // p_gen
  float p = s.x * Wpg[d] + s.y * Wpg[d + 1] + s.z * Wpg[d + 2] + s.w * Wpg[d + 3];
#pragma unroll
  for (int j = 0; j < 4; ++j) {
    int k = t + j * 256;
    p += hidden[(size_t)b * H2 + k] * Wpg[1024 + k];
  }
  p += ctxoutT4[(size_t)(t >> 2) * 256 + b * 4 + (t & 3)] * Wpg[2048 + t];
  p = wred_sum(p);
  __shared__ float red[4];
  if (lane == 0) red[w] = p;
  __syncthreads();
  if (t == 0) {
    float dd = red[0] + red[1] + red[2] + red[3] + bpg[0];
    pgen[b] = fsig(dd);
  }
}

// ---- pack inner into MFMA B-fragments ----
__global__ __launch_bounds__(256) void k_packinner(const float* __restrict__ innerT4,
                                                   short8* __restrict__ packB) {
  int f = blockIdx.x * 256 + threadIdx.x;  // < 4096
  int l = f & 63, bt = (f >> 6) & 3, ks = f >> 8;
  int b = bt * 16 + (l & 15);
  int kbase = ks * 32 + (l >> 4) * 8;
  float4 q0 = *(const float4*)&innerT4[(size_t)(kbase / 4) * 256 + b * 4];
  float4 q1 = *(const float4*)&innerT4[(size_t)(kbase / 4 + 1) * 256 + b * 4];
  short8 frag;
  frag[0] = f2bf(q0.x); frag[1] = f2bf(q0.y);
  frag[2] = f2bf(q0.z); frag[3] = f2bf(q0.w);
  frag[4] = f2bf(q1.x); frag[5] = f2bf(q1.y);
  frag[6] = f2bf(q1.z); frag[7] = f2bf(q1.w);
  packB[f] = frag;
}

// ---- logits via bf16 MFMA, bf16 logits store, fused softmax partials ----
__global__ __launch_bounds__(256) void k_mfma_logits(
    const float* __restrict__ W2, const short8* __restrict__ packB,
    const float* __restrict__ bias, unsigned short* __restrict__ logits_bf,
    float* __restrict__ mp, float* __restrict__ zp) {
  const int l = threadIdx.x;
  const int w = threadIdx.y;
  const int jblk = blockIdx.x * 64;
  const int jv = min(jblk + w * 16 + (l & 15), V - 1);
  const float4* wp4 = (const float4*)(W2 + (size_t)jv * 512 + (l >> 4) * 8);

  f32x4 acc0 = {0.f, 0.f, 0.f, 0.f}, acc1 = acc0, acc2 = acc0, acc3 = acc0;
  float4 cw0 = wp4[0], cw1 = wp4[1];
#pragma unroll
  for (int ks = 0; ks < 16; ++ks) {
    float4 nw0, nw1;
    if (ks < 15) { nw0 = wp4[(ks + 1) * 8]; nw1 = wp4[(ks + 1) * 8 + 1]; }
    short8 af;
    af[0] = f2bf(cw0.x); af[1] = f2bf(cw0.y); af[2] = f2bf(cw0.z); af[3] = f2bf(cw0.w);
    af[4] = f2bf(cw1.x); af[5] = f2bf(cw1.y); af[6] = f2bf(cw1.z); af[7] = f2bf(cw1.w);
    short8 b0 = packB[(ks * 4 + 0) * 64 + l];
    short8 b1 = packB[(ks * 4 + 1) * 64 + l];
    short8 b2 = packB[(ks * 4 + 2) * 64 + l];
    short8 b3 = packB[(ks * 4 + 3) * 64 + l];
    acc0 = __builtin_amdgcn_mfma_f32_16x16x32_bf16(af, b0, acc0, 0, 0, 0);
    acc1 = __builtin_amdgcn_mfma_f32_16x16x32_bf16(af, b1, acc1, 0, 0, 0);
    acc2 = __builtin_amdgcn_mfma_f32_16x16x32_bf16(af, b2, acc2, 0, 0, 0);
    acc3 = __builtin_amdgcn_mfma_f32_16x16x32_bf16(af, b3, acc3, 0, 0, 0);
    if (ks < 15) { cw0 = nw0; cw1 = nw1; }
  }

  __shared__ float tile[64][65];
  const int rbase = w * 16 + (l >> 4) * 4;
#pragma unroll
  for (int v = 0; v < 4; ++v) {
    int jl = rbase + v;
    int j = jblk + jl;
    float bv = bias[min(j, V - 1)];
    bool valid = (j < V);
    tile[jl][0 * 16 + (l & 15)] = valid ? acc0[v] + bv : -INFINITY;
    tile[jl][1 * 16 + (l & 15)] = valid ? acc1[v] + bv : -INFINITY;
    tile[jl][2 * 16 + (l & 15)] = valid ? acc2[v] + bv : -INFINITY;
    tile[jl][3 * 16 + (l & 15)] = valid ? acc3[v] + bv : -INFINITY;
  }
  __syncthreads();
  const int t = w * 64 + l;
#pragma unroll
  for (int i = 0; i < 16; ++i) {
    int idx = i * 256 + t;
    int jl = idx & 63;
    int b = idx >> 6;
    int j = jblk + jl;
    if (j < V)
      logits_bf[(size_t)b * V + j] = (unsigned short)f2bf(tile[jl][b]);
  }
  if (t < 64) {
    float m = -INFINITY;
#pragma unroll
    for (int jl = 0; jl < 64; ++jl) m = fmaxf(m, tile[jl][t]);
    float z = 0.f;
#pragma unroll
    for (int jl = 0; jl < 64; ++jl) z += __expf(tile[jl][t] - m);
    mp[(size_t)blockIdx.x * 64 + t] = m;
    zp[(size_t)blockIdx.x * 64 + t] = z;
  }
}

// ---- fused: (M,Z) reduce + vd = p_gen*softmax + LDS-hist scatter ----
__global__ __launch_bounds__(256) void k_vdms(
    const unsigned short* __restrict__ logits_bf, const float* __restrict__ mp,
    const float* __restrict__ zp, const float* __restrict__ pgen,
    const float* __restrict__ a_out, const int* __restrict__ tex,
    float* __restrict__ out) {
  const int b = blockIdx.x >> 3;
  const int c = blockIdx.x & 7;
  const int t = threadIdx.x;
  const int lane = t & 63, w = t >> 6;
  __shared__ float red[4];
  __shared__ float hist[6272];
  float m = -INFINITY;
  for (int i = t; i < NBLK_V; i += 256) m = fmaxf(m, mp[i * 64 + b]);
  m = wred_max(m);
  if (lane == 0) red[w] = m;
  __syncthreads();
  const float M = fmaxf(fmaxf(red[0], red[1]), fmaxf(red[2], red[3]));
  __syncthreads();
  float z = 0.f;
  for (int i = t; i < NBLK_V; i += 256) z += zp[i * 64 + b] * __expf(mp[i * 64 + b] - M);
  z = wred_sum(z);
  if (lane == 0) red[w] = z;
  __syncthreads();
  const float Z = red[0] + red[1] + red[2] + red[3];
  const float pg = pgen[b];
  const float scale = pg / Z;
  const float wq = 1.f - pg;
  const int v0 = c * 6272;
  const int v1 = min(v0 + 6272, VDN);
  for (int i = t; i < 6272; i += 256) hist[i] = 0.f;
  __syncthreads();
  for (int s = t; s < S; s += 256) {
    int v = tex[s * B + b];
    if (v >= v0 && v < v1) atomicAdd(&hist[v - v0], wq * a_out[s * B + b]);
  }
  __syncthreads();
  for (int v = v0 + t; v < v1; v += 256) {
    float val =
        (v < V) ? scale * __expf(bf2f(logits_bf[(size_t)b * V + v]) - M) : 0.f;
    out[(size_t)b * VDN + v] = val + hist[v - v0];
  }
}

extern "C" void kernel_launch(void* const* d_in, const int* in_sizes, int n_in,
                              void* d_out, int out_size, void* d_ws, size_t ws_size,
                              hipStream_t stream) {
  const int* sumin = (const int*)d_in[0];
  const float* h0 = (const float*)d_in[1];
  const float* c0 = (const float*)d_in[2];
  const float* enc_out = (const float*)d_in[3];
  const float* ef = (const float*)d_in[4];
  const float* mask = (const float*)d_in[5];
  const float* context = (const float*)d_in[6];
  const float* coverage = (const float*)d_in[7];
  const int* tex = (const int*)d_in[8];
  const float* emb = (const float*)d_in[10];
  const float* W_feat = (const float*)d_in[11];
  const float* b_feat = (const float*)d_in[12];
  const float* W_cov = (const float*)d_in[13];
  const float* b_cov = (const float*)d_in[14];
  const float* w_att = (const float*)d_in[15];
  const float* b_att = (const float*)d_in[16];
  const float* W_ih = (const float*)d_in[17];
  const float* W_hh = (const float*)d_in[18];
  const float* b_ih = (const float*)d_in[19];
  const float* b_hh = (const float*)d_in[20];
  const float* W_ctx = (const float*)d_in[21];
  const float* b_ctx = (const float*)d_in[22];
  const float* W_pg = (const float*)d_in[23];
  const float* b_pg = (const float*)d_in[24];
  const float* W_o1 = (const float*)d_in[25];
  const float* b_o1 = (const float*)d_in[26];
  const float* W_o2 = (const float*)d_in[27];
  const float* b_o2 = (const float*)d_in[28];

  float* out = (float*)d_out;
  float* vd = out;                           // [64][50100]
  float* hidden = vd + (size_t)B * VDN;      // [64][1024] = [h|c]
  float* ctx_new = hidden + (size_t)B * H2;  // [64][1024]
  float* a_out = ctx_new + (size_t)B * H2;   // [400][64]
  float* cov_out = a_out + (size_t)S * B;    // [400][64]

  float* ws = (float*)d_ws;
  float* catT4 = ws;                   // 81920
  float* h0T4 = catT4 + 81920;         // 32768
  float* ctxoutT4 = h0T4 + 32768;      // 16384
  float* gates = ctxoutT4 + 16384;     // 131072
  float* hidcatT4 = gates + 131072;    // 65536
  float* dfeat = hidcatT4 + 65536;     // 65536
  float* e_x = dfeat + 65536;          // 25600
  float* ctxnewT4 = e_x + 25600;       // 65536
  float* innerT4 = ctxnewT4 + 65536;   // 32768
  float* pgen = innerT4 + 32768;       // 64
  float* Zb = pgen + 64;               // 64
  float* mp = Zb + 64;                 // 50048
  float* zp = mp + 50048;              // 50048
  float* packBf = zp + 50048;          // 16384 floats = 4096 short8
  float* logits = packBf + 16384;      // 1600064 (bf16 area)
  float* partc = logits + 1600064;     // 50*65536 = 3276800
  short8* packB = (short8*)packBf;
  unsigned short* logits_bf = (unsigned short*)logits;

  dim3 gblk(64, 4);

  k_pre<<<1408, 256, 0, stream>>>(b_ctx, b_ih, b_hh, b_feat, b_o1, context, emb,
                                  sumin, h0, ctxoutT4, gates, dfeat, innerT4,
                                  catT4, h0T4, Zb);
  // ctx_out += [context|x] @ W_ctx.T   (T4 out)
  k_gemmsk<2, 64, 0><<<dim3(32, 5), gblk, 0, stream>>>(
      catT4, W_ctx, 1280, 5, nullptr, nullptr, 0, ctxoutT4, 0);
  // gates += ctx_out@W_ih.T  and  h0@W_hh.T   (row-major out)
  k_gemmsk<2, 64, 1><<<dim3(256, 3), gblk, 0, stream>>>(
      ctxoutT4, W_ih, 256, 1, h0T4, W_hh, 512, gates, 2048);
  k_lstm<<<128, 256, 0, stream>>>(gates, c0, hidden, hidcatT4);
  // dec_feat += hidden @ W_feat.T   (row-major out)
  k_gemmsk<2, 64, 1><<<dim3(128, 4), gblk, 0, stream>>>(
      hidcatT4, W_feat, 1024, 4, nullptr, nullptr, 0, dfeat, 1024);
  // fused attention scores + Z + unnormalized ctx partials (both streams)
  k_ectx<<<SC * B, 256, 0, stream>>>(ef, dfeat, coverage, W_cov, b_cov, w_att,
                                     b_att, mask, enc_out, e_x, Zb, partc);
  // reduce partials, normalize, p_gen, a_out/cov_out
  k_ctxpg<<<B, 256, 0, stream>>>(partc, e_x, Zb, coverage, hidden, ctxoutT4,
                                 W_pg, b_pg, ctx_new, ctxnewT4, pgen, a_out,
                                 cov_out);
  // inner += h@W_o1[:, :512].T  and  ctx_new@W_o1[:, 512:].T   (T4 out)
  k_gemmsk<2, 64, 0><<<dim3(64, 6), gblk, 0, stream>>>(
      hidcatT4, W_o1, 1536, 2, ctxnewT4, W_o1 + 512, 1536, innerT4, 0);
  k_packinner<<<16, 256, 0, stream>>>(innerT4, packB);
  k_mfma_logits<<<NBLK_V, gblk, 0, stream>>>(W_o2, packB, b_o2, logits_bf, mp, zp);
  // fused (M,Z) + vd write + LDS-hist scatter
  k_vdms<<<B * 8, 256, 0, stream>>>(logits_bf, mp, zp, pgen, a_out, tex, vd);
}

// Round 14
// 204.863 us; speedup vs baseline: 1.0316x; 1.0107x over previous
//
#include <hip/hip_runtime.h>
#include <cmath>

#define B 64
#define S 400
#define H 512
#define E 256
#define V 50000
#define OOV 100
#define H2 1024
#define VDN (V + OOV)   // 50100
#define NBLK_V 782      // ceil(V/64)
#define SC 10           // ctx partial chunks (40 s each, one per block)

typedef __attribute__((ext_vector_type(8))) short short8;
typedef __attribute__((ext_vector_type(4))) float f32x4;

__device__ __forceinline__ float wred_sum(float v) {
#pragma unroll
  for (int o = 32; o > 0; o >>= 1) v += __shfl_down(v, o, 64);
  return v;
}
__device__ __forceinline__ short f2bf(float f) {
  return __builtin_bit_cast(short, (__bf16)f);
}
__device__ __forceinline__ float bf2f(unsigned short u) {
  unsigned x = (unsigned)u << 16;
  return __builtin_bit_cast(float, x);
}
__device__ __forceinline__ float ftanh(float x) {
  float e = __expf(2.f * x);
  return 1.f - 2.f * __builtin_amdgcn_rcpf(e + 1.f);
}
__device__ __forceinline__ float fsig(float x) {
  return __builtin_amdgcn_rcpf(1.f + __expf(-x));
}
__device__ __forceinline__ float wred_max(float v) {
#pragma unroll
  for (int o = 32; o > 0; o >>= 1) v = fmaxf(v, __shfl_down(v, o, 64));
  return v;
}

// ---- fused: bias-init GEMM outputs + pack catT4/h0T4 + zero Zb ----
__global__ __launch_bounds__(256) void k_pre(
    const float* __restrict__ b_ctx, const float* __restrict__ b_ih,
    const float* __restrict__ b_hh, const float* __restrict__ b_feat,
    const float* __restrict__ b_o1, const float* __restrict__ context,
    const float* __restrict__ emb, const int* __restrict__ sumin,
    const float* __restrict__ h0, float* __restrict__ ctxoutT4,
    float* __restrict__ gates, float* __restrict__ dfeat,
    float* __restrict__ innerT4, float* __restrict__ catT4,
    float* __restrict__ h0T4, float* __restrict__ Zb) {
  int idx = blockIdx.x * 256 + threadIdx.x;  // < 360448
  if (idx < 64) Zb[idx] = 0.f;
  if (idx < 16384) {
    int j = ((idx >> 8) << 2) + (idx & 3);
    ctxoutT4[idx] = b_ctx[j];
  } else if (idx < 16384 + 131072) {
    int i = idx - 16384;
    int j = i & 2047;
    gates[i] = b_ih[j] + b_hh[j];
  } else if (idx < 16384 + 131072 + 65536) {
    int i = idx - 16384 - 131072;
    dfeat[i] = b_feat[i & 1023];
  } else if (idx < 245760) {
    int i = idx - 16384 - 131072 - 65536;
    int j = ((i >> 8) << 2) + (i & 3);
    innerT4[i] = b_o1[j];
  } else if (idx < 245760 + 81920) {
    int i = idx - 245760;
    int e = i & 3, b = (i >> 2) & 63, q = i >> 8;
    int k = q * 4 + e;
    catT4[i] = (k < 1024) ? context[b * 1024 + k]
                          : emb[(size_t)sumin[b] * 256 + (k - 1024)];
  } else {
    int i = idx - 245760 - 81920;  // < 32768
    int e = i & 3, b = (i >> 2) & 63, q = i >> 8;
    h0T4[i] = h0[b * 512 + q * 4 + e];
  }
}

// ---- split-K skinny GEMM, atomic accumulate into bias-initialized out ----
template <int R, int KC, int OUTMODE>
__global__ __launch_bounds__(256) void k_gemmsk(
    const float* __restrict__ A1, const float* __restrict__ W1, int ldw1, int s1,
    const float* __restrict__ A2, const float* __restrict__ W2, int ldw2,
    float* __restrict__ out, int ldout) {
  const int lane = threadIdx.x;
  const int w = threadIdx.y;
  const int j0 = blockIdx.x * (4 * R) + w * R;
  const float* A;
  const float* W;
  int ldw, kc0;
  if ((int)blockIdx.y < s1) {
    A = A1; W = W1; ldw = ldw1; kc0 = blockIdx.y * KC;
  } else {
    A = A2; W = W2; ldw = ldw2; kc0 = (blockIdx.y - s1) * KC;
  }
  float acc[R];
#pragma unroll
  for (int r = 0; r < R; ++r) acc[r] = 0.f;
  const float* ap = A + (size_t)kc0 * 256 + lane * 4;
  const float* wr[R];
#pragma unroll
  for (int r = 0; r < R; ++r) wr[r] = W + (size_t)(j0 + r) * ldw + kc0 * 4;
#pragma unroll 8
  for (int k4 = 0; k4 < KC; ++k4) {
    float4 av = *(const float4*)(ap + (size_t)k4 * 256);
#pragma unroll
    for (int r = 0; r < R; ++r) {
      float4 wv = *(const float4*)(wr[r] + k4 * 4);
      acc[r] += av.x * wv.x + av.y * wv.y + av.z * wv.z + av.w * wv.w;
    }
  }
#pragma unroll
  for (int r = 0; r < R; ++r) {
    int j = j0 + r;
    if constexpr (OUTMODE == 0)
      atomicAdd(&out[((size_t)(j >> 2) * 64 + lane) * 4 + (j & 3)], acc[r]);
    else
      atomicAdd(&out[(size_t)lane * ldout + j], acc[r]);
  }
}

// ---- LSTM pointwise: hidden=[h|c] row-major (d_out) + hidcat T4 ----
__global__ __launch_bounds__(256) void k_lstm(const float* __restrict__ gates,
                                              const float* __restrict__ c0,
                                              float* __restrict__ hidden,
                                              float* __restrict__ hcT4) {
  int idx = blockIdx.x * 256 + threadIdx.x;  // 32768
  int b = idx >> 9, u = idx & 511;
  float gi = gates[(size_t)b * 2048 + u];
  float gf = gates[(size_t)b * 2048 + 512 + u];
  float gg = gates[(size_t)b * 2048 + 1024 + u];
  float go = gates[(size_t)b * 2048 + 1536 + u];
  float c = fsig(gf) * c0[(size_t)b * 512 + u] + fsig(gi) * ftanh(gg);
  float h = fsig(go) * ftanh(c);
  hidden[(size_t)b * H2 + u] = h;
  hidden[(size_t)b * H2 + 512 + u] = c;
  hcT4[((u >> 2) * 64 + b) * 4 + (u & 3)] = h;
  int k = 512 + u;
  hcT4[((k >> 2) * 64 + b) * 4 + (k & 3)] = c;
}

// ---- wave-autonomous fused attention: e, x=mask*exp(e), Z, x·enc partials ----
// grid: g*64+b (g<10). Block = 4 waves; wave w owns rows s0..s0+9 of batch b.
// No __syncthreads in the hot loop; 16 loads in flight per 2-row iteration.
__global__ __launch_bounds__(256) void k_ectx(
    const float* __restrict__ ef, const float* __restrict__ dfeat,
    const float* __restrict__ cov, const float* __restrict__ Wcov,
    const float* __restrict__ bcov, const float* __restrict__ watt,
    const float* __restrict__ batt, const float* __restrict__ mask,
    const float* __restrict__ enc, float* __restrict__ e_x,
    float* __restrict__ Zb, float* __restrict__ partc) {
  const int t = threadIdx.x;
  const int lane = t & 63;
  const int w = t >> 6;
  const int b = blockIdx.x & 63;
  const int g = blockIdx.x >> 6;  // 0..9
  const int s0 = g * 40 + w * 10;
  // lane-invariants: f4 slot k*64+lane, k<4 (covers the 1024-float row)
  float4 dbc[4], wc4[4], wa4[4];
  {
    const float4* dfr = (const float4*)(dfeat + (size_t)b * H2);
    const float4* bcr = (const float4*)bcov;
    const float4* wcr = (const float4*)Wcov;
    const float4* war = (const float4*)watt;
#pragma unroll
    for (int k = 0; k < 4; ++k) {
      int i4 = k * 64 + lane;
      float4 dv = dfr[i4], bc = bcr[i4];
      dbc[k] = make_float4(dv.x + bc.x, dv.y + bc.y, dv.z + bc.z, dv.w + bc.w);
      wc4[k] = wcr[i4];
      wa4[k] = war[i4];
    }
  }
  const float ba = batt[0];
  float4 acc[4];
#pragma unroll
  for (int k = 0; k < 4; ++k) acc[k] = make_float4(0.f, 0.f, 0.f, 0.f);
  float zsum = 0.f;

  for (int i = 0; i < 10; i += 2) {
    const int s1 = s0 + i, s2 = s0 + i + 1;
    const float4* efr1 = (const float4*)(ef + (size_t)(s1 * B + b) * H2);
    const float4* efr2 = (const float4*)(ef + (size_t)(s2 * B + b) * H2);
    const float4* enr1 = (const float4*)(enc + ((size_t)b * S + s1) * H2);
    const float4* enr2 = (const float4*)(enc + ((size_t)b * S + s2) * H2);
    float4 a1[4], a2[4], e1[4], e2[4];
#pragma unroll
    for (int k = 0; k < 4; ++k) {
      int i4 = k * 64 + lane;
      a1[k] = efr1[i4];
      a2[k] = efr2[i4];
      e1[k] = enr1[i4];
      e2[k] = enr2[i4];
    }
    const float c1 = cov[s1 * B + b], c2 = cov[s2 * B + b];
    float d1 = 0.f, d2 = 0.f;
#pragma unroll
    for (int k = 0; k < 4; ++k) {
      d1 += ftanh(a1[k].x + dbc[k].x + c1 * wc4[k].x) * wa4[k].x;
      d1 += ftanh(a1[k].y + dbc[k].y + c1 * wc4[k].y) * wa4[k].y;
      d1 += ftanh(a1[k].z + dbc[k].z + c1 * wc4[k].z) * wa4[k].z;
      d1 += ftanh(a1[k].w + dbc[k].w + c1 * wc4[k].w) * wa4[k].w;
      d2 += ftanh(a2[k].x + dbc[k].x + c2 * wc4[k].x) * wa4[k].x;
      d2 += ftanh(a2[k].y + dbc[k].y + c2 * wc4[k].y) * wa4[k].y;
      d2 += ftanh(a2[k].z + dbc[k].z + c2 * wc4[k].z) * wa4[k].z;
      d2 += ftanh(a2[k].w + dbc[k].w + c2 * wc4[k].w) * wa4[k].w;
    }
    // butterfly: every lane gets the full sum (no LDS, no barrier)
#pragma unroll
    for (int o = 32; o > 0; o >>= 1) {
      d1 += __shfl_xor(d1, o, 64);
      d2 += __shfl_xor(d2, o, 64);
    }
    const float x1 = mask[s1 * B + b] * __expf(d1 + ba);
    const float x2 = mask[s2 * B + b] * __expf(d2 + ba);
    if (lane == 0) {
      e_x[s1 * B + b] = x1;
      e_x[s2 * B + b] = x2;
    }
    zsum += x1 + x2;
#pragma unroll
    for (int k = 0; k < 4; ++k) {
      acc[k].x += x1 * e1[k].x + x2 * e2[k].x;
      acc[k].y += x1 * e1[k].y + x2 * e2[k].y;
      acc[k].z += x1 * e1[k].z + x2 * e2[k].z;
      acc[k].w += x1 * e1[k].w + x2 * e2[k].w;
    }
  }
  if (lane == 0) atomicAdd(&Zb[b], zsum);
  // block-reduce 4 wave accumulators -> one partial per block
  __shared__ float4 lacc[4][256];
#pragma unroll
  for (int k = 0; k < 4; ++k) lacc[w][lane * 4 + k] = acc[k];
  __syncthreads();
  if (w == 0) {
#pragma unroll
    for (int k = 0; k < 4; ++k) {
      float4 s = lacc[0][lane * 4 + k];
      float4 s1 = lacc[1][lane * 4 + k];
      float4 s2 = lacc[2][lane * 4 + k];
      float4 s3 = lacc[3][lane * 4 + k];
      s.x += s1.x + s2.x + s3.x;
      s.y += s1.y + s2.y + s3.y;
      s.z += s1.z + s2.z + s3.z;
      s.w += s1.w + s2.w + s3.w;
      ((float4*)(partc + (size_t)blockIdx.x * H2))[k * 64 + lane] = s;
    }
  }
}

// ---- fused: reduce 10 partials, scale 1/Z -> ctx outputs + p_gen + a/cov ----
__global__ __launch_bounds__(256) void k_ctxpg(
    const float* __restrict__ partc, const float* __restrict__ e_x,
    const float* __restrict__ Zb, const float* __restrict__ coverage,
    const float* __restrict__ hidden, const float* __restrict__ ctxoutT4,
    const float* __restrict__ Wpg, const float* __restrict__ bpg,
    float* __restrict__ ctx_new, float* __restrict__ ctxT4,
    float* __restrict__ pgen, float* __restrict__ a_out,
    float* __restrict__ cov_out) {
  const int b = blockIdx.x;
  const int t = threadIdx.x;
  const int lane = t & 63, w = t >> 6;
  const float rZ = 1.f / Zb[b];
  const int d = t * 4;
  float4 s = make_float4(0.f, 0.f, 0.f, 0.f);
#pragma unroll
  for (int sc = 0; sc < SC; ++sc) {
    float4 v = *(const float4*)(partc + (size_t)(sc * 64 + b) * H2 + d);
    s.x += v.x; s.y += v.y; s.z += v.z; s.w += v.w;
  }
  s.x *= rZ; s.y *= rZ; s.z *= rZ; s.w *= rZ;
  *(float4*)(ctx_new + (size_t)b * H2 + d) = s;
  *(float4*)(ctxT4 + (size_t)t * 256 + b * 4) = s;
#pragma unroll
  for (int i = 0; i < 2; ++i) {
    int sidx = t + i * 256;
    if (sidx < S) {
      int sb = sidx * B + b;
      float av = e_x[sb] * rZ;
      a_out[sb] = av;
      cov_out[sb] = coverage[sb] + av;
    }
  }
  float p = s.x * Wpg[d] + s.y * Wpg[d + 1] + s.z * Wpg[d + 2] + s.w * Wpg[d + 3];
#pragma unroll
  for (int j = 0; j < 4; ++j) {
    int k = t + j * 256;
    p += hidden[(size_t)b * H2 + k] * Wpg[1024 + k];
  }
  p += ctxoutT4[(size_t)(t >> 2) * 256 + b * 4 + (t & 3)] * Wpg[2048 + t];
  p = wred_sum(p);
  __shared__ float red[4];
  if (lane == 0) red[w] = p;
  __syncthreads();
  if (t == 0) {
    float dd = red[0] + red[1] + red[2] + red[3] + bpg[0];
    pgen[b] = fsig(dd);
  }
}

// ---- pack inner into MFMA B-fragments ----
__global__ __launch_bounds__(256) void k_packinner(const float* __restrict__ innerT4,
                                                   short8* __restrict__ packB) {
  int f = blockIdx.x * 256 + threadIdx.x;  // < 4096
  int l = f & 63, bt = (f >> 6) & 3, ks = f >> 8;
  int b = bt * 16 + (l & 15);
  int kbase = ks * 32 + (l >> 4) * 8;
  float4 q0 = *(const float4*)&innerT4[(size_t)(kbase / 4) * 256 + b * 4];
  float4 q1 = *(const float4*)&innerT4[(size_t)(kbase / 4 + 1) * 256 + b * 4];
  short8 frag;
  frag[0] = f2bf(q0.x); frag[1] = f2bf(q0.y);
  frag[2] = f2bf(q0.z); frag[3] = f2bf(q0.w);
  frag[4] = f2bf(q1.x); frag[5] = f2bf(q1.y);
  frag[6] = f2bf(q1.z); frag[7] = f2bf(q1.w);
  packB[f] = frag;
}

// ---- logits via bf16 MFMA, bf16 logits store, fused softmax partials ----
__global__ __launch_bounds__(256) void k_mfma_logits(
    const float* __restrict__ W2, const short8* __restrict__ packB,
    const float* __restrict__ bias, unsigned short* __restrict__ logits_bf,
    float* __restrict__ mp, float* __restrict__ zp) {
  const int l = threadIdx.x;
  const int w = threadIdx.y;
  const int jblk = blockIdx.x * 64;
  const int jv = min(jblk + w * 16 + (l & 15), V - 1);
  const float4* wp4 = (const float4*)(W2 + (size_t)jv * 512 + (l >> 4) * 8);

  f32x4 acc0 = {0.f, 0.f, 0.f, 0.f}, acc1 = acc0, acc2 = acc0, acc3 = acc0;
  float4 cw0 = wp4[0], cw1 = wp4[1];
#pragma unroll
  for (int ks = 0; ks < 16; ++ks) {
    float4 nw0, nw1;
    if (ks < 15) { nw0 = wp4[(ks + 1) * 8]; nw1 = wp4[(ks + 1) * 8 + 1]; }
    short8 af;
    af[0] = f2bf(cw0.x); af[1] = f2bf(cw0.y); af[2] = f2bf(cw0.z); af[3] = f2bf(cw0.w);
    af[4] = f2bf(cw1.x); af[5] = f2bf(cw1.y); af[6] = f2bf(cw1.z); af[7] = f2bf(cw1.w);
    short8 b0 = packB[(ks * 4 + 0) * 64 + l];
    short8 b1 = packB[(ks * 4 + 1) * 64 + l];
    short8 b2 = packB[(ks * 4 + 2) * 64 + l];
    short8 b3 = packB[(ks * 4 + 3) * 64 + l];
    acc0 = __builtin_amdgcn_mfma_f32_16x16x32_bf16(af, b0, acc0, 0, 0, 0);
    acc1 = __builtin_amdgcn_mfma_f32_16x16x32_bf16(af, b1, acc1, 0, 0, 0);
    acc2 = __builtin_amdgcn_mfma_f32_16x16x32_bf16(af, b2, acc2, 0, 0, 0);
    acc3 = __builtin_amdgcn_mfma_f32_16x16x32_bf16(af, b3, acc3, 0, 0, 0);
    if (ks < 15) { cw0 = nw0; cw1 = nw1; }
  }

  __shared__ float tile[64][65];
  const int rbase = w * 16 + (l >> 4) * 4;
#pragma unroll
  for (int v = 0; v < 4; ++v) {
    int jl = rbase + v;
    int j = jblk + jl;
    float bv = bias[min(j, V - 1)];
    bool valid = (j < V);
    tile[jl][0 * 16 + (l & 15)] = valid ? acc0[v] + bv : -INFINITY;
    tile[jl][1 * 16 + (l & 15)] = valid ? acc1[v] + bv : -INFINITY;
    tile[jl][2 * 16 + (l & 15)] = valid ? acc2[v] + bv : -INFINITY;
    tile[jl][3 * 16 + (l & 15)] = valid ? acc3[v] + bv : -INFINITY;
  }
  __syncthreads();
  const int t = w * 64 + l;
#pragma unroll
  for (int i = 0; i < 16; ++i) {
    int idx = i * 256 + t;
    int jl = idx & 63;
    int b = idx >> 6;
    int j = jblk + jl;
    if (j < V)
      logits_bf[(size_t)b * V + j] = (unsigned short)f2bf(tile[jl][b]);
  }
  if (t < 64) {
    float m = -INFINITY;
#pragma unroll
    for (int jl = 0; jl < 64; ++jl) m = fmaxf(m, tile[jl][t]);
    float z = 0.f;
#pragma unroll
    for (int jl = 0; jl < 64; ++jl) z += __expf(tile[jl][t] - m);
    mp[(size_t)blockIdx.x * 64 + t] = m;
    zp[(size_t)blockIdx.x * 64 + t] = z;
  }
}

// ---- fused: (M,Z) reduce + vd = p_gen*softmax + LDS-hist scatter ----
__global__ __launch_bounds__(256) void k_vdms(
    const unsigned short* __restrict__ logits_bf, const float* __restrict__ mp,
    const float* __restrict__ zp, const float* __restrict__ pgen,
    const float* __restrict__ a_out, const int* __restrict__ tex,
    float* __restrict__ out) {
  const int b = blockIdx.x >> 3;
  const int c = blockIdx.x & 7;
  const int t = threadIdx.x;
  const int lane = t & 63, w = t >> 6;
  __shared__ float red[4];
  __shared__ float hist[6272];
  float m = -INFINITY;
  for (int i = t; i < NBLK_V; i += 256) m = fmaxf(m, mp[i * 64 + b]);
  m = wred_max(m);
  if (lane == 0) red[w] = m;
  __syncthreads();
  const float M = fmaxf(fmaxf(red[0], red[1]), fmaxf(red[2], red[3]));
  __syncthreads();
  float z = 0.f;
  for (int i = t; i < NBLK_V; i += 256) z += zp[i * 64 + b] * __expf(mp[i * 64 + b] - M);
  z = wred_sum(z);
  if (lane == 0) red[w] = z;
  __syncthreads();
  const float Z = red[0] + red[1] + red[2] + red[3];
  const float pg = pgen[b];
  const float scale = pg / Z;
  const float wq = 1.f - pg;
  const int v0 = c * 6272;
  const int v1 = min(v0 + 6272, VDN);
  for (int i = t; i < 6272; i += 256) hist[i] = 0.f;
  __syncthreads();
  for (int s = t; s < S; s += 256) {
    int v = tex[s * B + b];
    if (v >= v0 && v < v1) atomicAdd(&hist[v - v0], wq * a_out[s * B + b]);
  }
  __syncthreads();
  for (int v = v0 + t; v < v1; v += 256) {
    float val =
        (v < V) ? scale * __expf(bf2f(logits_bf[(size_t)b * V + v]) - M) : 0.f;
    out[(size_t)b * VDN + v] = val + hist[v - v0];
  }
}

extern "C" void kernel_launch(void* const* d_in, const int* in_sizes, int n_in,
                              void* d_out, int out_size, void* d_ws, size_t ws_size,
                              hipStream_t stream) {
  const int* sumin = (const int*)d_in[0];
  const float* h0 = (const float*)d_in[1];
  const float* c0 = (const float*)d_in[2];
  const float* enc_out = (const float*)d_in[3];
  const float* ef = (const float*)d_in[4];
  const float* mask = (const float*)d_in[5];
  const float* context = (const float*)d_in[6];
  const float* coverage = (const float*)d_in[7];
  const int* tex = (const int*)d_in[8];
  const float* emb = (const float*)d_in[10];
  const float* W_feat = (const float*)d_in[11];
  const float* b_feat = (const float*)d_in[12];
  const float* W_cov = (const float*)d_in[13];
  const float* b_cov = (const float*)d_in[14];
  const float* w_att = (const float*)d_in[15];
  const float* b_att = (const float*)d_in[16];
  const float* W_ih = (const float*)d_in[17];
  const float* W_hh = (const float*)d_in[18];
  const float* b_ih = (const float*)d_in[19];
  const float* b_hh = (const float*)d_in[20];
  const float* W_ctx = (const float*)d_in[21];
  const float* b_ctx = (const float*)d_in[22];
  const float* W_pg = (const float*)d_in[23];
  const float* b_pg = (const float*)d_in[24];
  const float* W_o1 = (const float*)d_in[25];
  const float* b_o1 = (const float*)d_in[26];
  const float* W_o2 = (const float*)d_in[27];
  const float* b_o2 = (const float*)d_in[28];

  float* out = (float*)d_out;
  float* vd = out;                           // [64][50100]
  float* hidden = vd + (size_t)B * VDN;      // [64][1024] = [h|c]
  float* ctx_new = hidden + (size_t)B * H2;  // [64][1024]
  float* a_out = ctx_new + (size_t)B * H2;   // [400][64]
  float* cov_out = a_out + (size_t)S * B;    // [400][64]

  float* ws = (float*)d_ws;
  float* catT4 = ws;                   // 81920
  float* h0T4 = catT4 + 81920;         // 32768
  float* ctxoutT4 = h0T4 + 32768;      // 16384
  float* gates = ctxoutT4 + 16384;     // 131072
  float* hidcatT4 = gates + 131072;    // 65536
  float* dfeat = hidcatT4 + 65536;     // 65536
  float* e_x = dfeat + 65536;          // 25600
  float* ctxnewT4 = e_x + 25600;       // 65536
  float* innerT4 = ctxnewT4 + 65536;   // 32768
  float* pgen = innerT4 + 32768;       // 64
  float* Zb = pgen + 64;               // 64
  float* mp = Zb + 64;                 // 50048
  float* zp = mp + 50048;              // 50048
  float* packBf = zp + 50048;          // 16384 floats = 4096 short8
  float* logits = packBf + 16384;      // 1600064 (bf16 area)
  float* partc = logits + 1600064;     // 10*64*1024 = 655360
  short8* packB = (short8*)packBf;
  unsigned short* logits_bf = (unsigned short*)logits;

  dim3 gblk(64, 4);

  k_pre<<<1408, 256, 0, stream>>>(b_ctx, b_ih, b_hh, b_feat, b_o1, context, emb,
                                  sumin, h0, ctxoutT4, gates, dfeat, innerT4,
                                  catT4, h0T4, Zb);
  // ctx_out += [context|x] @ W_ctx.T   (T4 out)
  k_gemmsk<2, 64, 0><<<dim3(32, 5), gblk, 0, stream>>>(
      catT4, W_ctx, 1280, 5, nullptr, nullptr, 0, ctxoutT4, 0);
  // gates += ctx_out@W_ih.T  and  h0@W_hh.T   (row-major out)
  k_gemmsk<2, 64, 1><<<dim3(256, 3), gblk, 0, stream>>>(
      ctxoutT4, W_ih, 256, 1, h0T4, W_hh, 512, gates, 2048);
  k_lstm<<<128, 256, 0, stream>>>(gates, c0, hidden, hidcatT4);
  // dec_feat += hidden @ W_feat.T   (row-major out)
  k_gemmsk<2, 64, 1><<<dim3(128, 4), gblk, 0, stream>>>(
      hidcatT4, W_feat, 1024, 4, nullptr, nullptr, 0, dfeat, 1024);
  // wave-autonomous fused attention (both 105MB streams, no barriers)
  k_ectx<<<SC * B, 256, 0, stream>>>(ef, dfeat, coverage, W_cov, b_cov, w_att,
                                     b_att, mask, enc_out, e_x, Zb, partc);
  // reduce partials, normalize, p_gen, a_out/cov_out
  k_ctxpg<<<B, 256, 0, stream>>>(partc, e_x, Zb, coverage, hidden, ctxoutT4,
                                 W_pg, b_pg, ctx_new, ctxnewT4, pgen, a_out,
                                 cov_out);
  // inner += h@W_o1[:, :512].T  and  ctx_new@W_o1[:, 512:].T   (T4 out)
  k_gemmsk<2, 64, 0><<<dim3(64, 6), gblk, 0, stream>>>(
      hidcatT4, W_o1, 1536, 2, ctxnewT4, W_o1 + 512, 1536, innerT4, 0);
  k_packinner<<<16, 256, 0, stream>>>(innerT4, packB);
  k_mfma_logits<<<NBLK_V, gblk, 0, stream>>>(W_o2, packB, b_o2, logits_bf, mp, zp);
  // fused (M,Z) + vd write + LDS-hist scatter
  k_vdms<<<B * 8, 256, 0, stream>>>(logits_bf, mp, zp, pgen, a_out, tex, vd);
}